// Round 3
// baseline (709.063 us; speedup 1.0000x reference)
//
#include <hip/hip_runtime.h>

#define HH 56
#define WW2 56
#define WS 7
#define SHIFT 3
#define HEADS 4
#define DIM 128
#define NTOK 49
#define BATCH 64
#define TOKENS (BATCH*HH*WW2)   // 200704
#define NWIN 64                 // windows per image (8x8)
#define WINDOWS (BATCH*NWIN)    // 4096

typedef __bf16 bf16x8 __attribute__((ext_vector_type(8)));
typedef float  f32x4  __attribute__((ext_vector_type(4)));

__device__ __forceinline__ unsigned short f2bf(float f) {
  unsigned u = __float_as_uint(f);
  u += 0x7fffu + ((u >> 16) & 1u);
  return (unsigned short)(u >> 16);
}

__device__ __forceinline__ float bf2f(unsigned short h) {
  return __uint_as_float(((unsigned)h) << 16);
}

__device__ __forceinline__ void st4(unsigned short* p, float a, float b, float c, float d) {
  ushort4 pk; pk.x = f2bf(a); pk.y = f2bf(b); pk.z = f2bf(c); pk.w = f2bf(d);
  *(ushort4*)p = pk;
}

__device__ __forceinline__ int reg3(int g) { return g >= 53 ? 2 : (g >= 49 ? 1 : 0); }

// ---------------- weight prep: transpose + bf16 ----------------
__global__ __launch_bounds__(256) void k_prep(
    const float* __restrict__ qkv_w, const float* __restrict__ proj_w,
    const float* __restrict__ w1, const float* __restrict__ w2,
    unsigned short* __restrict__ qkvwT, unsigned short* __restrict__ projwT,
    unsigned short* __restrict__ w1T, unsigned short* __restrict__ w2T)
{
  int idx = blockIdx.x * 256 + threadIdx.x;
  if (idx < 49152) {                       // qkv_w [128][384] -> qkvwT [384][128]
    int n = idx >> 7, k = idx & 127;
    qkvwT[idx] = f2bf(qkv_w[k * 384 + n]);
  } else if (idx < 65536) {                // proj_w [128][128] -> projwT [128][128]
    int i = idx - 49152; int n = i >> 7, k = i & 127;
    projwT[i] = f2bf(proj_w[k * 128 + n]);
  } else if (idx < 131072) {               // mlp_w1 [128][512] -> w1T [512][128]
    int i = idx - 65536; int n = i >> 7, k = i & 127;
    w1T[i] = f2bf(w1[k * 512 + n]);
  } else {                                 // mlp_w2 [512][128] -> w2T [128][512]
    int i = idx - 131072; int n = i >> 9, k = i & 511;
    w2T[i] = f2bf(w2[k * 128 + n]);
  }
}

// ---------------- bias+mask table: [cls][head][qtoken 64][ktoken 64] fp32 ----------------
__global__ __launch_bounds__(256) void k_tbl(const float* __restrict__ rpb, float* __restrict__ tbl)
{
  int idx = blockIdx.x * 256 + threadIdx.x;   // 65536 entries
  int kt = idx & 63, qt = (idx >> 6) & 63, h = (idx >> 12) & 3, cls = idx >> 14;
  float v;
  if (qt >= NTOK || kt >= NTOK) v = -3e38f;
  else {
    int qi = qt / 7, qj = qt % 7, ki = kt / 7, kj = kt % 7;
    int bi = (cls & 2) ? 49 : 0, bj = (cls & 1) ? 49 : 0;
    int rq = reg3(bi + qi) * 3 + reg3(bj + qj);
    int rk = reg3(bi + ki) * 3 + reg3(bj + kj);
    v = rpb[((qi - ki + 6) * 13 + (qj - kj + 6)) * HEADS + h] + (rq != rk ? -100.0f : 0.0f);
  }
  tbl[idx] = v;
}

// ---------------- fused LN1 + shift/window + attention ----------------
__global__ __launch_bounds__(256, 2) void k_attn(
    const float* __restrict__ x,
    const float* __restrict__ n1w, const float* __restrict__ n1b,
    const unsigned short* __restrict__ qkvwT,
    const float* __restrict__ qkv_b,
    const unsigned short* __restrict__ projwT,
    const float* __restrict__ proj_b,
    const float* __restrict__ tbl,
    unsigned short* __restrict__ attn_out)
{
  // LDS: 17408 + 33792 + 18432 = 69632 B -> 2 blocks/CU
  __shared__ __align__(16) unsigned short s_x[64 * 136];   // LN'd x tile; then PV [token][d]
  __shared__ __align__(16) unsigned short s_qk[64 * 264];  // q|k [token][dim]; then P [qtok][ktok]
  __shared__ __align__(16) unsigned short s_vT[128 * 72];  // v^T [d][token]; then proj-out stage

  int tid = threadIdx.x;
  int wave = tid >> 6;
  int lane = tid & 63;
  int l = lane & 15, g = lane >> 4;
  int win = blockIdx.x;
  int bi = win >> 6, wi = (win >> 3) & 7, wj = win & 7;

  // ---- phase 0: LN1 + gather window tokens (shifted) into s_x ----
  {
    int c = lane & 31, th = lane >> 5;
    float4 wv = *(const float4*)(n1w + c * 4);
    float4 bv = *(const float4*)(n1b + c * 4);
    #pragma unroll
    for (int it = 0; it < 7; ++it) {
      int tok = it * 8 + wave * 2 + th;
      if (tok < NTOK) {
        int ti = tok / 7, tj = tok % 7;
        int si = wi * 7 + ti, sj = wj * 7 + tj;
        int i = si + SHIFT; if (i >= HH) i -= HH;
        int j = sj + SHIFT; if (j >= WW2) j -= WW2;
        const float* xp = x + ((size_t)bi * (HH * WW2) + i * WW2 + j) * DIM + c * 4;
        float4 v = *(const float4*)xp;
        float s = (v.x + v.y) + (v.z + v.w);
        float sq = (v.x * v.x + v.y * v.y) + (v.z * v.z + v.w * v.w);
        #pragma unroll
        for (int off = 1; off <= 16; off <<= 1) {
          s += __shfl_xor(s, off);
          sq += __shfl_xor(sq, off);
        }
        float mean = s * (1.0f / DIM);
        float var = sq * (1.0f / DIM) - mean * mean;
        float rs = rsqrtf(var + 1e-5f);
        st4(&s_x[tok * 136 + c * 4],
            (v.x - mean) * rs * wv.x + bv.x, (v.y - mean) * rs * wv.y + bv.y,
            (v.z - mean) * rs * wv.z + bv.z, (v.w - mean) * rs * wv.w + bv.w);
      }
    }
  }
  for (int idx = tid; idx < 15 * 17; idx += 256) {
    int row = 49 + idx / 17, seg = idx % 17;
    *(uint4*)&s_x[row * 136 + seg * 8] = make_uint4(0, 0, 0, 0);
  }
  __syncthreads();

  // ---- phase 1: QKV^T GEMM: A=weights [wcol][k], B=x [token][k], D=[wcol][token] ----
  bf16x8 xf[4][4];   // [nt(token tile)][kk]
  #pragma unroll
  for (int nt = 0; nt < 4; ++nt)
    #pragma unroll
    for (int kk = 0; kk < 4; ++kk)
      xf[nt][kk] = *(const bf16x8*)&s_x[(nt * 16 + l) * 136 + kk * 32 + g * 8];

  #pragma unroll
  for (int wti = 0; wti < 6; ++wti) {
    int wt = wave * 6 + wti;                 // m-tile over 384 wcols
    bf16x8 wf[4];
    #pragma unroll
    for (int kk = 0; kk < 4; ++kk)
      wf[kk] = *(const bf16x8*)(qkvwT + (size_t)(wt * 16 + l) * DIM + kk * 32 + g * 8);
    f32x4 acc[4];
    #pragma unroll
    for (int nt = 0; nt < 4; ++nt) acc[nt] = (f32x4){0.f, 0.f, 0.f, 0.f};
    #pragma unroll
    for (int kk = 0; kk < 4; ++kk)
      #pragma unroll
      for (int nt = 0; nt < 4; ++nt)
        acc[nt] = __builtin_amdgcn_mfma_f32_16x16x32_bf16(wf[kk], xf[nt][kk], acc[nt], 0, 0, 0);
    float4 b4 = *(const float4*)(qkv_b + wt * 16 + g * 4);
    if (wt < 16) {           // q (wt<8) and k
      float sc = wt < 8 ? 0.17677669529663687f : 1.0f;
      #pragma unroll
      for (int nt = 0; nt < 4; ++nt)
        st4(&s_qk[(nt * 16 + l) * 264 + wt * 16 + g * 4],
            (acc[nt][0] + b4.x) * sc, (acc[nt][1] + b4.y) * sc,
            (acc[nt][2] + b4.z) * sc, (acc[nt][3] + b4.w) * sc);
    } else {                 // v -> v^T [d][token]
      int d0 = wt * 16 - 256 + g * 4;
      #pragma unroll
      for (int nt = 0; nt < 4; ++nt) {
        s_vT[(d0 + 0) * 72 + nt * 16 + l] = f2bf(acc[nt][0] + b4.x);
        s_vT[(d0 + 1) * 72 + nt * 16 + l] = f2bf(acc[nt][1] + b4.y);
        s_vT[(d0 + 2) * 72 + nt * 16 + l] = f2bf(acc[nt][2] + b4.z);
        s_vT[(d0 + 3) * 72 + nt * 16 + l] = f2bf(acc[nt][3] + b4.w);
      }
    }
  }
  __syncthreads();

  // ---- phase 2: S^T = K.Q^T with table C-init; in-register softmax; P [qtok][ktok] ----
  int h = wave;
  bf16x8 kf[4], qf[4];
  #pragma unroll
  for (int mt = 0; mt < 4; ++mt)
    kf[mt] = *(const bf16x8*)&s_qk[(mt * 16 + l) * 264 + 128 + h * 32 + g * 8];
  #pragma unroll
  for (int nt = 0; nt < 4; ++nt)
    qf[nt] = *(const bf16x8*)&s_qk[(nt * 16 + l) * 264 + h * 32 + g * 8];
  __syncthreads();   // all q/k fragment reads done; s_qk reusable as P

  int clsid = ((wi == 7) ? 2 : 0) | ((wj == 7) ? 1 : 0);
  const float* tb = tbl + ((clsid * 4 + h) << 12);
  f32x4 sc[4][4];    // [mt=ktok tile][nt=qtok tile]
  #pragma unroll
  for (int nt = 0; nt < 4; ++nt)
    #pragma unroll
    for (int mt = 0; mt < 4; ++mt) {
      f32x4 ci = *(const f32x4*)(tb + (nt * 16 + l) * 64 + mt * 16 + g * 4);
      sc[mt][nt] = __builtin_amdgcn_mfma_f32_16x16x32_bf16(kf[mt], qf[nt], ci, 0, 0, 0);
    }

  #pragma unroll
  for (int nt = 0; nt < 4; ++nt) {
    float m = sc[0][nt][0];
    #pragma unroll
    for (int mt = 0; mt < 4; ++mt)
      #pragma unroll
      for (int rr = 0; rr < 4; ++rr) m = fmaxf(m, sc[mt][nt][rr]);
    m = fmaxf(m, __shfl_xor(m, 16));
    m = fmaxf(m, __shfl_xor(m, 32));
    float ssum = 0.f;
    #pragma unroll
    for (int mt = 0; mt < 4; ++mt)
      #pragma unroll
      for (int rr = 0; rr < 4; ++rr) {
        float e = __expf(sc[mt][nt][rr] - m);
        sc[mt][nt][rr] = e;
        ssum += e;
      }
    ssum += __shfl_xor(ssum, 16);
    ssum += __shfl_xor(ssum, 32);
    float inv = 1.0f / ssum;
    #pragma unroll
    for (int mt = 0; mt < 4; ++mt)
      st4(&s_qk[(nt * 16 + l) * 264 + h * 64 + mt * 16 + g * 4],
          sc[mt][nt][0] * inv, sc[mt][nt][1] * inv, sc[mt][nt][2] * inv, sc[mt][nt][3] * inv);
  }
  // P write->read is same-wave; compiler orders via lgkmcnt.

  // ---- phase 3: PV^T: A=v^T [d][ktok], B=P [qtok][ktok], D=[d][qtok] -> s_x[token][d] ----
  bf16x8 vf[2][2], pf[4][2];
  #pragma unroll
  for (int dt = 0; dt < 2; ++dt)
    #pragma unroll
    for (int kk = 0; kk < 2; ++kk)
      vf[dt][kk] = *(const bf16x8*)&s_vT[(h * 32 + dt * 16 + l) * 72 + kk * 32 + g * 8];
  #pragma unroll
  for (int nt = 0; nt < 4; ++nt)
    #pragma unroll
    for (int kk = 0; kk < 2; ++kk)
      pf[nt][kk] = *(const bf16x8*)&s_qk[(nt * 16 + l) * 264 + h * 64 + kk * 32 + g * 8];
  #pragma unroll
  for (int dt = 0; dt < 2; ++dt)
    #pragma unroll
    for (int nt = 0; nt < 4; ++nt) {
      f32x4 a = (f32x4){0.f, 0.f, 0.f, 0.f};
      a = __builtin_amdgcn_mfma_f32_16x16x32_bf16(vf[dt][0], pf[nt][0], a, 0, 0, 0);
      a = __builtin_amdgcn_mfma_f32_16x16x32_bf16(vf[dt][1], pf[nt][1], a, 0, 0, 0);
      st4(&s_x[(nt * 16 + l) * 136 + h * 32 + dt * 16 + g * 4], a[0], a[1], a[2], a[3]);
    }
  __syncthreads();

  // ---- phase 4: proj^T: A=projW^T [pcol][d], B=PV [token][d], D=[pcol][token] ----
  unsigned short* stage = s_vT;   // 64x136 fits in 128x72 region
  bf16x8 of[4][4];
  #pragma unroll
  for (int nt = 0; nt < 4; ++nt)
    #pragma unroll
    for (int kk = 0; kk < 4; ++kk)
      of[nt][kk] = *(const bf16x8*)&s_x[(nt * 16 + l) * 136 + kk * 32 + g * 8];
  #pragma unroll
  for (int wti = 0; wti < 2; ++wti) {
    int wt = wave * 2 + wti;
    bf16x8 wf[4];
    #pragma unroll
    for (int kk = 0; kk < 4; ++kk)
      wf[kk] = *(const bf16x8*)(projwT + (size_t)(wt * 16 + l) * DIM + kk * 32 + g * 8);
    f32x4 acc[4];
    #pragma unroll
    for (int nt = 0; nt < 4; ++nt) acc[nt] = (f32x4){0.f, 0.f, 0.f, 0.f};
    #pragma unroll
    for (int kk = 0; kk < 4; ++kk)
      #pragma unroll
      for (int nt = 0; nt < 4; ++nt)
        acc[nt] = __builtin_amdgcn_mfma_f32_16x16x32_bf16(wf[kk], of[nt][kk], acc[nt], 0, 0, 0);
    float4 b4 = *(const float4*)(proj_b + wt * 16 + g * 4);
    #pragma unroll
    for (int nt = 0; nt < 4; ++nt)
      st4(&stage[(nt * 16 + l) * 136 + wt * 16 + g * 4],
          acc[nt][0] + b4.x, acc[nt][1] + b4.y, acc[nt][2] + b4.z, acc[nt][3] + b4.w);
  }
  __syncthreads();

  unsigned short* outp = attn_out + (size_t)win * (NTOK * DIM);
  for (int idx = tid; idx < NTOK * 16; idx += 256) {
    int row = idx >> 4, seg = idx & 15;
    *(uint4*)(outp + idx * 8) = *(const uint4*)&stage[row * 136 + seg * 8];
  }
}

__device__ __forceinline__ float gelu_f(float x) {
  float y = 0.7978845608028654f * x * (1.0f + 0.044715f * x * x);
  float e = __expf(-2.0f * fabsf(y));
  float t = __fdividef(1.0f - e, 1.0f + e);
  t = copysignf(t, y);
  return 0.5f * x * (1.0f + t);
}

// ---------------- fused residual + LN2 + MLP (barrier-free wave-private core) ----------------
// out = z + gelu(ln2(z)@w1+b1)@w2 + b2, z = x + window_reverse(attn_o)
__global__ __launch_bounds__(256, 2) void k_mlp(
    const float* __restrict__ x,
    const unsigned short* __restrict__ attn_o,
    const float* __restrict__ n2w, const float* __restrict__ n2b,
    const unsigned short* __restrict__ w1T, const float* __restrict__ b1,
    const unsigned short* __restrict__ w2T, const float* __restrict__ b2,
    float* __restrict__ out)
{
  // LDS: 33792 + 17408 + 17408 = 68608 B -> 2 blocks/CU
  __shared__ __align__(16) float s_z[64 * 132];             // residual, fp32, padded stride
  __shared__ __align__(16) unsigned short s_h[64 * 136];    // ln2 output, bf16
  __shared__ __align__(16) unsigned short s_t[4][16 * 136]; // per-wave private gelu buffer

  int tid = threadIdx.x;
  int wave = tid >> 6;
  int lane = tid & 63;
  int l = lane & 15, g = lane >> 4;
  int t0 = blockIdx.x * 64;

  // ---- phase 0: z = x + gather(attn); LN2 -> s_h; z -> s_z ----
  {
    int c = lane & 31, th = lane >> 5;
    float4 wv = *(const float4*)(n2w + c * 4);
    float4 bv = *(const float4*)(n2b + c * 4);
    #pragma unroll
    for (int it = 0; it < 8; ++it) {
      int tl = it * 8 + wave * 2 + th;
      int t = t0 + tl;
      int bi = t / (HH * WW2);
      int r = t % (HH * WW2);
      int i = r / WW2, j = r % WW2;
      int si = i >= SHIFT ? i - SHIFT : i + (HH - SHIFT);
      int sj = j >= SHIFT ? j - SHIFT : j + (WW2 - SHIFT);
      int win = bi * NWIN + (si / WS) * 8 + (sj / WS);
      int tok = (si % WS) * WS + (sj % WS);
      float4 v = *(const float4*)(x + (size_t)t * DIM + c * 4);
      ushort4 a = *(const ushort4*)(attn_o + ((size_t)(win * NTOK + tok)) * DIM + c * 4);
      float z0 = v.x + bf2f(a.x), z1 = v.y + bf2f(a.y);
      float z2 = v.z + bf2f(a.z), z3 = v.w + bf2f(a.w);
      float s = (z0 + z1) + (z2 + z3);
      float sq = (z0 * z0 + z1 * z1) + (z2 * z2 + z3 * z3);
      #pragma unroll
      for (int off = 1; off <= 16; off <<= 1) {
        s += __shfl_xor(s, off);
        sq += __shfl_xor(sq, off);
      }
      float mean = s * (1.0f / DIM);
      float var = sq * (1.0f / DIM) - mean * mean;
      float rs = rsqrtf(var + 1e-5f);
      *(float4*)&s_z[tl * 132 + c * 4] = make_float4(z0, z1, z2, z3);
      st4(&s_h[tl * 136 + c * 4],
          (z0 - mean) * rs * wv.x + bv.x, (z1 - mean) * rs * wv.y + bv.y,
          (z2 - mean) * rs * wv.z + bv.z, (z3 - mean) * rs * wv.w + bv.w);
    }
  }
  __syncthreads();

  // ---- barrier-free MLP core: wave owns tokens [wave*16, wave*16+16) ----
  int rb = wave * 16;
  unsigned short* stw = &s_t[wave][0];
  bf16x8 hf[4];
  #pragma unroll
  for (int kk = 0; kk < 4; ++kk)
    hf[kk] = *(const bf16x8*)&s_h[(rb + l) * 136 + kk * 32 + g * 8];

  f32x4 o[8];
  #pragma unroll
  for (int wt2 = 0; wt2 < 8; ++wt2) o[wt2] = (f32x4){0.f, 0.f, 0.f, 0.f};

  #pragma unroll
  for (int ch = 0; ch < 4; ++ch) {
    // GEMM1 chunk: D[intercol][token] for intercols [ch*128, ch*128+128)
    #pragma unroll
    for (int wt = 0; wt < 8; ++wt) {
      int n0 = ch * 128 + wt * 16;
      bf16x8 wf[4];
      #pragma unroll
      for (int kk = 0; kk < 4; ++kk)
        wf[kk] = *(const bf16x8*)(w1T + (size_t)(n0 + l) * DIM + kk * 32 + g * 8);
      f32x4 acc = (f32x4){0.f, 0.f, 0.f, 0.f};
      #pragma unroll
      for (int kk = 0; kk < 4; ++kk)
        acc = __builtin_amdgcn_mfma_f32_16x16x32_bf16(wf[kk], hf[kk], acc, 0, 0, 0);
      float4 b4 = *(const float4*)(b1 + n0 + g * 4);
      st4(&stw[l * 136 + wt * 16 + g * 4],
          gelu_f(acc[0] + b4.x), gelu_f(acc[1] + b4.y),
          gelu_f(acc[2] + b4.z), gelu_f(acc[3] + b4.w));
    }
    // GEMM2 chunk: o[outcol][token] += w2 . t   (same-wave LDS, no barrier)
    #pragma unroll
    for (int k2 = 0; k2 < 4; ++k2) {
      bf16x8 tf = *(const bf16x8*)&stw[l * 136 + k2 * 32 + g * 8];
      #pragma unroll
      for (int wt2 = 0; wt2 < 8; ++wt2) {
        bf16x8 wf2 = *(const bf16x8*)(w2T + (size_t)(wt2 * 16 + l) * 512 + ch * 128 + k2 * 32 + g * 8);
        o[wt2] = __builtin_amdgcn_mfma_f32_16x16x32_bf16(wf2, tf, o[wt2], 0, 0, 0);
      }
    }
  }

  // ---- epilogue: out = z + o + b2 (pure write) ----
  #pragma unroll
  for (int wt2 = 0; wt2 < 8; ++wt2) {
    float4 zq = *(const float4*)&s_z[(rb + l) * 132 + wt2 * 16 + g * 4];
    float4 b4 = *(const float4*)(b2 + wt2 * 16 + g * 4);
    float4 ov;
    ov.x = zq.x + o[wt2][0] + b4.x;
    ov.y = zq.y + o[wt2][1] + b4.y;
    ov.z = zq.z + o[wt2][2] + b4.z;
    ov.w = zq.w + o[wt2][3] + b4.w;
    *(float4*)(out + (size_t)(t0 + rb + l) * DIM + wt2 * 16 + g * 4) = ov;
  }
}

extern "C" void kernel_launch(void* const* d_in, const int* in_sizes, int n_in,
                              void* d_out, int out_size, void* d_ws, size_t ws_size,
                              hipStream_t stream) {
  const float* x       = (const float*)d_in[0];
  const float* qkv_w   = (const float*)d_in[1];
  const float* qkv_b   = (const float*)d_in[2];
  const float* proj_w  = (const float*)d_in[3];
  const float* proj_b  = (const float*)d_in[4];
  const float* rpb     = (const float*)d_in[5];
  const float* n1w     = (const float*)d_in[6];
  const float* n1b     = (const float*)d_in[7];
  const float* n2w     = (const float*)d_in[8];
  const float* n2b     = (const float*)d_in[9];
  const float* mlp_w1  = (const float*)d_in[10];
  const float* mlp_b1  = (const float*)d_in[11];
  const float* mlp_w2  = (const float*)d_in[12];
  const float* mlp_b2  = (const float*)d_in[13];
  float* out = (float*)d_out;

  char* ws = (char*)d_ws;
  const size_t TOKB = (size_t)TOKENS * DIM * 2;     // 51,380,224 B
  unsigned short* attn_o = (unsigned short*)(ws);
  unsigned short* qkvwT  = (unsigned short*)(ws + TOKB);
  unsigned short* projwT = (unsigned short*)(ws + TOKB + 98304);
  unsigned short* w1T    = (unsigned short*)(ws + TOKB + 98304 + 32768);
  unsigned short* w2T    = (unsigned short*)(ws + TOKB + 98304 + 32768 + 131072);
  float*          tbl    = (float*)(ws + TOKB + 98304 + 32768 + 131072 + 131072);  // 262144 B

  k_prep<<<768, 256, 0, stream>>>(qkv_w, proj_w, mlp_w1, mlp_w2, qkvwT, projwT, w1T, w2T);
  k_tbl<<<256, 256, 0, stream>>>(rpb, tbl);
  k_attn<<<WINDOWS, 256, 0, stream>>>(x, n1w, n1b, qkvwT, qkv_b, projwT, proj_b, tbl, attn_o);
  k_mlp<<<TOKENS / 64, 256, 0, stream>>>(x, attn_o, n2w, n2b, w1T, mlp_b1, w2T, mlp_b2, out);
}

// Round 4
// 588.647 us; speedup vs baseline: 1.2046x; 1.2046x over previous
//
#include <hip/hip_runtime.h>
#include <hip/hip_bf16.h>

#define HH 56
#define WW2 56
#define WS 7
#define SHIFT 3
#define HEADS 4
#define DIM 128
#define NTOK 49
#define BATCH 64
#define TOKENS (BATCH*HH*WW2)   // 200704
#define NWIN 64                 // windows per image (8x8)
#define WINDOWS (BATCH*NWIN)    // 4096

typedef __bf16 bf16x8 __attribute__((ext_vector_type(8)));
typedef float  f32x4  __attribute__((ext_vector_type(4)));

__device__ __forceinline__ unsigned short f2bf(float f) {
  unsigned u = __float_as_uint(f);
  u += 0x7fffu + ((u >> 16) & 1u);
  return (unsigned short)(u >> 16);
}

__device__ __forceinline__ float bf2f(unsigned short h) {
  return __uint_as_float(((unsigned)h) << 16);
}

// HW packed f32->bf16 (v_cvt_pk_bf16_f32 on gfx950), RNE
__device__ __forceinline__ unsigned pk2(float a, float b) {
  __hip_bfloat162 h = __float22bfloat162_rn(make_float2(a, b));
  unsigned u;
  __builtin_memcpy(&u, &h, 4);
  return u;
}

__device__ __forceinline__ void st4(unsigned short* p, float a, float b, float c, float d) {
  uint2 v; v.x = pk2(a, b); v.y = pk2(c, d);
  *(uint2*)p = v;
}

__device__ __forceinline__ void st8(unsigned short* p, const float* y) {
  uint4 v; v.x = pk2(y[0], y[1]); v.y = pk2(y[2], y[3]);
  v.z = pk2(y[4], y[5]); v.w = pk2(y[6], y[7]);
  *(uint4*)p = v;
}

__device__ __forceinline__ int reg3(int g) { return g >= 53 ? 2 : (g >= 49 ? 1 : 0); }

// ---------------- weight prep: transpose + bf16 ----------------
__global__ __launch_bounds__(256) void k_prep(
    const float* __restrict__ qkv_w, const float* __restrict__ proj_w,
    const float* __restrict__ w1, const float* __restrict__ w2,
    unsigned short* __restrict__ qkvwT, unsigned short* __restrict__ projwT,
    unsigned short* __restrict__ w1T, unsigned short* __restrict__ w2T)
{
  int idx = blockIdx.x * 256 + threadIdx.x;
  if (idx < 49152) {
    int n = idx >> 7, k = idx & 127;
    qkvwT[idx] = f2bf(qkv_w[k * 384 + n]);
  } else if (idx < 65536) {
    int i = idx - 49152; int n = i >> 7, k = i & 127;
    projwT[i] = f2bf(proj_w[k * 128 + n]);
  } else if (idx < 131072) {
    int i = idx - 65536; int n = i >> 7, k = i & 127;
    w1T[i] = f2bf(w1[k * 512 + n]);
  } else {
    int i = idx - 131072; int n = i >> 9, k = i & 511;
    w2T[i] = f2bf(w2[k * 128 + n]);
  }
}

// ---------------- bias+mask table: [cls][head][qtoken 64][ktoken 64] fp32 ----------------
__global__ __launch_bounds__(256) void k_tbl(const float* __restrict__ rpb, float* __restrict__ tbl)
{
  int idx = blockIdx.x * 256 + threadIdx.x;   // 65536 entries
  int kt = idx & 63, qt = (idx >> 6) & 63, h = (idx >> 12) & 3, cls = idx >> 14;
  float v;
  if (qt >= NTOK || kt >= NTOK) v = -3e38f;
  else {
    int qi = qt / 7, qj = qt % 7, ki = kt / 7, kj = kt % 7;
    int bi = (cls & 2) ? 49 : 0, bj = (cls & 1) ? 49 : 0;
    int rq = reg3(bi + qi) * 3 + reg3(bj + qj);
    int rk = reg3(bi + ki) * 3 + reg3(bj + kj);
    v = rpb[((qi - ki + 6) * 13 + (qj - kj + 6)) * HEADS + h] + (rq != rk ? -100.0f : 0.0f);
  }
  tbl[idx] = v;
}

// ---------------- fused LN1 + shift/window + attention ----------------
// LDS budget 51200 B -> 3 blocks/CU
__global__ __launch_bounds__(256, 3) void k_attn(
    const float* __restrict__ x,
    const float* __restrict__ n1w, const float* __restrict__ n1b,
    const unsigned short* __restrict__ qkvwT,
    const float* __restrict__ qkv_b,
    const unsigned short* __restrict__ projwT,
    const float* __restrict__ proj_b,
    const float* __restrict__ tbl,
    unsigned short* __restrict__ attn_out)
{
  __shared__ __align__(16) unsigned short s_qk[64 * 264];  // q|k; then P; then PV(c0-127)+stage(c128-255)
  __shared__ __align__(16) unsigned short s_xv[64 * 136];  // x tile [tok][136]; then v^T flat [128][68]

  int tid = threadIdx.x;
  int wave = tid >> 6;
  int lane = tid & 63;
  int l = lane & 15, g = lane >> 4;
  int win = blockIdx.x;
  int bi = win >> 6, wi = (win >> 3) & 7, wj = win & 7;

  // ---- phase 0: LN1 + shifted-window gather; 16 lanes per token, 8 cols each ----
  {
    int t16 = lane >> 4, c16 = lane & 15;
    float4 wva = *(const float4*)(n1w + c16 * 8);
    float4 wvb = *(const float4*)(n1w + c16 * 8 + 4);
    float4 bva = *(const float4*)(n1b + c16 * 8);
    float4 bvb = *(const float4*)(n1b + c16 * 8 + 4);
    #pragma unroll
    for (int it = 0; it < 4; ++it) {
      int tok = it * 16 + wave * 4 + t16;
      unsigned short* dst = &s_xv[tok * 136 + c16 * 8];
      if (tok < NTOK) {
        int ti = tok / 7, tj = tok - ti * 7;
        int i = wi * 7 + ti + SHIFT; if (i >= HH) i -= HH;
        int j = wj * 7 + tj + SHIFT; if (j >= WW2) j -= WW2;
        const float* xp = x + ((size_t)bi * (HH * WW2) + i * WW2 + j) * DIM + c16 * 8;
        float4 va = *(const float4*)xp;
        float4 vb = *(const float4*)(xp + 4);
        float s = ((va.x + va.y) + (va.z + va.w)) + ((vb.x + vb.y) + (vb.z + vb.w));
        float sq = ((va.x*va.x + va.y*va.y) + (va.z*va.z + va.w*va.w))
                 + ((vb.x*vb.x + vb.y*vb.y) + (vb.z*vb.z + vb.w*vb.w));
        #pragma unroll
        for (int off = 1; off <= 8; off <<= 1) {
          s += __shfl_xor(s, off);
          sq += __shfl_xor(sq, off);
        }
        float mean = s * (1.0f / DIM);
        float var = sq * (1.0f / DIM) - mean * mean;
        float rs = rsqrtf(var + 1e-5f);
        float y[8];
        y[0] = (va.x - mean) * rs * wva.x + bva.x;
        y[1] = (va.y - mean) * rs * wva.y + bva.y;
        y[2] = (va.z - mean) * rs * wva.z + bva.z;
        y[3] = (va.w - mean) * rs * wva.w + bva.w;
        y[4] = (vb.x - mean) * rs * wvb.x + bvb.x;
        y[5] = (vb.y - mean) * rs * wvb.y + bvb.y;
        y[6] = (vb.z - mean) * rs * wvb.z + bvb.z;
        y[7] = (vb.w - mean) * rs * wvb.w + bvb.w;
        st8(dst, y);
      } else {
        *(uint4*)dst = make_uint4(0, 0, 0, 0);
      }
    }
  }
  __syncthreads();

  // ---- load x fragments, then free s_xv for v^T ----
  bf16x8 xf[4][4];
  #pragma unroll
  for (int nt = 0; nt < 4; ++nt)
    #pragma unroll
    for (int kk = 0; kk < 4; ++kk)
      xf[nt][kk] = *(const bf16x8*)&s_xv[(nt * 16 + l) * 136 + kk * 32 + g * 8];
  __syncthreads();

  // ---- phase 1: QKV^T GEMM: D=[wcol][token]; q,k -> s_qk; v^T -> s_xv[d*68+t] ----
  #pragma unroll
  for (int wti = 0; wti < 6; ++wti) {
    int wt = wave * 6 + wti;
    bf16x8 wf[4];
    #pragma unroll
    for (int kk = 0; kk < 4; ++kk)
      wf[kk] = *(const bf16x8*)(qkvwT + (size_t)(wt * 16 + l) * DIM + kk * 32 + g * 8);
    f32x4 acc[4];
    #pragma unroll
    for (int nt = 0; nt < 4; ++nt) acc[nt] = (f32x4){0.f, 0.f, 0.f, 0.f};
    #pragma unroll
    for (int kk = 0; kk < 4; ++kk)
      #pragma unroll
      for (int nt = 0; nt < 4; ++nt)
        acc[nt] = __builtin_amdgcn_mfma_f32_16x16x32_bf16(wf[kk], xf[nt][kk], acc[nt], 0, 0, 0);
    float4 b4 = *(const float4*)(qkv_b + wt * 16 + g * 4);
    if (wt < 16) {           // q (wt<8, scaled) and k
      float sc = wt < 8 ? 0.17677669529663687f : 1.0f;
      #pragma unroll
      for (int nt = 0; nt < 4; ++nt)
        st4(&s_qk[(nt * 16 + l) * 264 + wt * 16 + g * 4],
            (acc[nt][0] + b4.x) * sc, (acc[nt][1] + b4.y) * sc,
            (acc[nt][2] + b4.z) * sc, (acc[nt][3] + b4.w) * sc);
    } else {                 // v -> v^T flat [d][68]
      int d0 = wt * 16 - 256 + g * 4;
      #pragma unroll
      for (int nt = 0; nt < 4; ++nt) {
        s_xv[(d0 + 0) * 68 + nt * 16 + l] = f2bf(acc[nt][0] + b4.x);
        s_xv[(d0 + 1) * 68 + nt * 16 + l] = f2bf(acc[nt][1] + b4.y);
        s_xv[(d0 + 2) * 68 + nt * 16 + l] = f2bf(acc[nt][2] + b4.z);
        s_xv[(d0 + 3) * 68 + nt * 16 + l] = f2bf(acc[nt][3] + b4.w);
      }
    }
  }
  __syncthreads();

  // ---- phase 2: S^T = K.Q^T with table C-init; softmax (no max pass); P [qtok][ktok] ----
  int h = wave;
  bf16x8 kf[4], qf[4];
  #pragma unroll
  for (int mt = 0; mt < 4; ++mt)
    kf[mt] = *(const bf16x8*)&s_qk[(mt * 16 + l) * 264 + 128 + h * 32 + g * 8];
  #pragma unroll
  for (int nt = 0; nt < 4; ++nt)
    qf[nt] = *(const bf16x8*)&s_qk[(nt * 16 + l) * 264 + h * 32 + g * 8];
  __syncthreads();   // all q/k reads done -> s_qk reusable as P

  int clsid = ((wi == 7) ? 2 : 0) | ((wj == 7) ? 1 : 0);
  const float* tb = tbl + ((clsid * 4 + h) << 12);
  f32x4 sc[4][4];    // [mt=ktok tile][nt=qtok tile]
  #pragma unroll
  for (int nt = 0; nt < 4; ++nt)
    #pragma unroll
    for (int mt = 0; mt < 4; ++mt) {
      f32x4 ci = *(const f32x4*)(tb + (nt * 16 + l) * 64 + mt * 16 + g * 4);
      sc[mt][nt] = __builtin_amdgcn_mfma_f32_16x16x32_bf16(kf[mt], qf[nt], ci, 0, 0, 0);
    }

  // scores are bounded (|qk|~1, bias small, mask -100, pad -3e38) -> exp without max
  // pad q-rows give sum=0 -> NaN, confined to stage rows >=49 (never stored out)
  #pragma unroll
  for (int nt = 0; nt < 4; ++nt) {
    float ssum = 0.f;
    #pragma unroll
    for (int mt = 0; mt < 4; ++mt)
      #pragma unroll
      for (int rr = 0; rr < 4; ++rr) {
        float e = __expf(sc[mt][nt][rr]);
        sc[mt][nt][rr] = e;
        ssum += e;
      }
    ssum += __shfl_xor(ssum, 16);
    ssum += __shfl_xor(ssum, 32);
    float inv = 1.0f / ssum;
    #pragma unroll
    for (int mt = 0; mt < 4; ++mt)
      st4(&s_qk[(nt * 16 + l) * 264 + h * 64 + mt * 16 + g * 4],
          sc[mt][nt][0] * inv, sc[mt][nt][1] * inv, sc[mt][nt][2] * inv, sc[mt][nt][3] * inv);
  }

  // ---- phase 3: PV^T: A=v^T, B=P, D=[d][qtok] -> s_qk cols 0-127 as [token][d] ----
  bf16x8 vf[2][2], pf[4][2];
  #pragma unroll
  for (int dt = 0; dt < 2; ++dt)
    #pragma unroll
    for (int kk = 0; kk < 2; ++kk)
      vf[dt][kk] = *(const bf16x8*)&s_xv[(h * 32 + dt * 16 + l) * 68 + kk * 32 + g * 8];
  #pragma unroll
  for (int nt = 0; nt < 4; ++nt)
    #pragma unroll
    for (int kk = 0; kk < 2; ++kk)
      pf[nt][kk] = *(const bf16x8*)&s_qk[(nt * 16 + l) * 264 + h * 64 + kk * 32 + g * 8];
  __syncthreads();   // all P reads done -> PV may overwrite P region

  #pragma unroll
  for (int dt = 0; dt < 2; ++dt)
    #pragma unroll
    for (int nt = 0; nt < 4; ++nt) {
      f32x4 a = (f32x4){0.f, 0.f, 0.f, 0.f};
      a = __builtin_amdgcn_mfma_f32_16x16x32_bf16(vf[dt][0], pf[nt][0], a, 0, 0, 0);
      a = __builtin_amdgcn_mfma_f32_16x16x32_bf16(vf[dt][1], pf[nt][1], a, 0, 0, 0);
      st4(&s_qk[(nt * 16 + l) * 264 + h * 32 + dt * 16 + g * 4], a[0], a[1], a[2], a[3]);
    }
  __syncthreads();

  // ---- phase 4: proj^T: D=[pcol][token] -> stage at s_qk cols 128-255 ----
  bf16x8 of[4][4];
  #pragma unroll
  for (int nt = 0; nt < 4; ++nt)
    #pragma unroll
    for (int kk = 0; kk < 4; ++kk)
      of[nt][kk] = *(const bf16x8*)&s_qk[(nt * 16 + l) * 264 + kk * 32 + g * 8];
  #pragma unroll
  for (int wti = 0; wti < 2; ++wti) {
    int wt = wave * 2 + wti;
    bf16x8 wf[4];
    #pragma unroll
    for (int kk = 0; kk < 4; ++kk)
      wf[kk] = *(const bf16x8*)(projwT + (size_t)(wt * 16 + l) * DIM + kk * 32 + g * 8);
    f32x4 acc[4];
    #pragma unroll
    for (int nt = 0; nt < 4; ++nt) acc[nt] = (f32x4){0.f, 0.f, 0.f, 0.f};
    #pragma unroll
    for (int kk = 0; kk < 4; ++kk)
      #pragma unroll
      for (int nt = 0; nt < 4; ++nt)
        acc[nt] = __builtin_amdgcn_mfma_f32_16x16x32_bf16(wf[kk], of[nt][kk], acc[nt], 0, 0, 0);
    float4 b4 = *(const float4*)(proj_b + wt * 16 + g * 4);
    #pragma unroll
    for (int nt = 0; nt < 4; ++nt)
      st4(&s_qk[(nt * 16 + l) * 264 + 128 + wt * 16 + g * 4],
          acc[nt][0] + b4.x, acc[nt][1] + b4.y, acc[nt][2] + b4.z, acc[nt][3] + b4.w);
  }
  __syncthreads();

  unsigned short* outp = attn_out + (size_t)win * (NTOK * DIM);
  for (int idx = tid; idx < NTOK * 16; idx += 256) {
    int row = idx >> 4, seg = idx & 15;
    *(uint4*)(outp + idx * 8) = *(const uint4*)&s_qk[row * 264 + 128 + seg * 8];
  }
}

__device__ __forceinline__ float gelu_f(float x) {
  // sigmoid approximation: x * sigmoid(1.702 x)
  float e = __expf(-1.702f * x);
  return x * __frcp_rn(1.0f + e);
}

// ---------------- fused residual + LN2 + MLP (block-cooperative, 4 blocks/CU) ----------------
// out = z + gelu(ln2(z)@w1+b1)@w2 + b2, z = x + window_reverse(attn_o); z recomputed in epilogue
__global__ __launch_bounds__(256, 4) void k_mlp(
    const float* __restrict__ x,
    const unsigned short* __restrict__ attn_o,
    const float* __restrict__ n2w, const float* __restrict__ n2b,
    const unsigned short* __restrict__ w1T, const float* __restrict__ b1,
    const unsigned short* __restrict__ w2T, const float* __restrict__ b2,
    float* __restrict__ out)
{
  // LDS: 17408 + 17408 = 34816 B -> 4 blocks/CU
  __shared__ __align__(16) unsigned short s_h[64 * 136];    // ln2 output, bf16
  __shared__ __align__(16) unsigned short s_t[64 * 136];    // gelu intermediate per chunk

  int tid = threadIdx.x;
  int wave = tid >> 6;
  int lane = tid & 63;
  int l = lane & 15, g = lane >> 4;
  int t0 = blockIdx.x * 64;

  // ---- phase 0: z = x + gather(attn); LN2 -> s_h (z NOT stored; recomputed in epilogue) ----
  {
    int t16 = lane >> 4, c16 = lane & 15;
    float4 wva = *(const float4*)(n2w + c16 * 8);
    float4 wvb = *(const float4*)(n2w + c16 * 8 + 4);
    float4 bva = *(const float4*)(n2b + c16 * 8);
    float4 bvb = *(const float4*)(n2b + c16 * 8 + 4);
    #pragma unroll
    for (int it = 0; it < 4; ++it) {
      int tl = it * 16 + wave * 4 + t16;
      int t = t0 + tl;
      int bi = t / (HH * WW2);
      int r = t % (HH * WW2);
      int i = r / WW2, j = r % WW2;
      int si = i >= SHIFT ? i - SHIFT : i + (HH - SHIFT);
      int sj = j >= SHIFT ? j - SHIFT : j + (WW2 - SHIFT);
      int win = bi * NWIN + (si / WS) * 8 + (sj / WS);
      int tok = (si % WS) * WS + (sj % WS);
      const float* xp = x + (size_t)t * DIM + c16 * 8;
      const unsigned short* ap = attn_o + ((size_t)(win * NTOK + tok)) * DIM + c16 * 8;
      float4 va = *(const float4*)xp;
      float4 vb = *(const float4*)(xp + 4);
      ushort4 aa = *(const ushort4*)ap;
      ushort4 ab = *(const ushort4*)(ap + 4);
      float z[8];
      z[0] = va.x + bf2f(aa.x); z[1] = va.y + bf2f(aa.y);
      z[2] = va.z + bf2f(aa.z); z[3] = va.w + bf2f(aa.w);
      z[4] = vb.x + bf2f(ab.x); z[5] = vb.y + bf2f(ab.y);
      z[6] = vb.z + bf2f(ab.z); z[7] = vb.w + bf2f(ab.w);
      float s = ((z[0]+z[1])+(z[2]+z[3])) + ((z[4]+z[5])+(z[6]+z[7]));
      float sq = ((z[0]*z[0]+z[1]*z[1])+(z[2]*z[2]+z[3]*z[3]))
               + ((z[4]*z[4]+z[5]*z[5])+(z[6]*z[6]+z[7]*z[7]));
      #pragma unroll
      for (int off = 1; off <= 8; off <<= 1) {
        s += __shfl_xor(s, off);
        sq += __shfl_xor(sq, off);
      }
      float mean = s * (1.0f / DIM);
      float var = sq * (1.0f / DIM) - mean * mean;
      float rs = rsqrtf(var + 1e-5f);
      float y[8];
      y[0] = (z[0]-mean)*rs*wva.x + bva.x; y[1] = (z[1]-mean)*rs*wva.y + bva.y;
      y[2] = (z[2]-mean)*rs*wva.z + bva.z; y[3] = (z[3]-mean)*rs*wva.w + bva.w;
      y[4] = (z[4]-mean)*rs*wvb.x + bvb.x; y[5] = (z[5]-mean)*rs*wvb.y + bvb.y;
      y[6] = (z[6]-mean)*rs*wvb.z + bvb.z; y[7] = (z[7]-mean)*rs*wvb.w + bvb.w;
      st8(&s_h[tl * 136 + c16 * 8], y);
    }
  }
  __syncthreads();

  bf16x8 hf[4][4];
  #pragma unroll
  for (int nt = 0; nt < 4; ++nt)
    #pragma unroll
    for (int kk = 0; kk < 4; ++kk)
      hf[nt][kk] = *(const bf16x8*)&s_h[(nt * 16 + l) * 136 + kk * 32 + g * 8];

  f32x4 o[2][4];
  #pragma unroll
  for (int wti = 0; wti < 2; ++wti)
    #pragma unroll
    for (int nt = 0; nt < 4; ++nt) o[wti][nt] = (f32x4){0.f, 0.f, 0.f, 0.f};

  #pragma unroll 1
  for (int c = 0; c < 4; ++c) {
    // GEMM1^T chunk: D[intercol][token], gelu -> s_t[token][intercol-local]
    #pragma unroll
    for (int wti = 0; wti < 2; ++wti) {
      int wt = wave * 2 + wti;
      int n0 = c * 128 + wt * 16;
      bf16x8 wf[4];
      #pragma unroll
      for (int kk = 0; kk < 4; ++kk)
        wf[kk] = *(const bf16x8*)(w1T + (size_t)(n0 + l) * DIM + kk * 32 + g * 8);
      f32x4 acc[4];
      #pragma unroll
      for (int nt = 0; nt < 4; ++nt) acc[nt] = (f32x4){0.f, 0.f, 0.f, 0.f};
      #pragma unroll
      for (int kk = 0; kk < 4; ++kk)
        #pragma unroll
        for (int nt = 0; nt < 4; ++nt)
          acc[nt] = __builtin_amdgcn_mfma_f32_16x16x32_bf16(wf[kk], hf[nt][kk], acc[nt], 0, 0, 0);
      float4 b4 = *(const float4*)(b1 + n0 + g * 4);
      #pragma unroll
      for (int nt = 0; nt < 4; ++nt)
        st4(&s_t[(nt * 16 + l) * 136 + wt * 16 + g * 4],
            gelu_f(acc[nt][0] + b4.x), gelu_f(acc[nt][1] + b4.y),
            gelu_f(acc[nt][2] + b4.z), gelu_f(acc[nt][3] + b4.w));
    }
    __syncthreads();
    // GEMM2^T chunk: o[outcol][token] += w2 . t
    #pragma unroll
    for (int kk = 0; kk < 4; ++kk) {
      bf16x8 tf[4];
      #pragma unroll
      for (int nt = 0; nt < 4; ++nt)
        tf[nt] = *(const bf16x8*)&s_t[(nt * 16 + l) * 136 + kk * 32 + g * 8];
      #pragma unroll
      for (int wti = 0; wti < 2; ++wti) {
        int wt = wave * 2 + wti;
        bf16x8 wf2 = *(const bf16x8*)(w2T + (size_t)(wt * 16 + l) * 512 + c * 128 + kk * 32 + g * 8);
        #pragma unroll
        for (int nt = 0; nt < 4; ++nt)
          o[wti][nt] = __builtin_amdgcn_mfma_f32_16x16x32_bf16(wf2, tf[nt], o[wti][nt], 0, 0, 0);
      }
    }
    __syncthreads();
  }

  // ---- epilogue: recompute z (L2-hot re-read) and write out = z + o + b2 ----
  #pragma unroll
  for (int nt = 0; nt < 4; ++nt) {
    int tl = nt * 16 + l;
    int t = t0 + tl;
    int bi = t / (HH * WW2);
    int r = t % (HH * WW2);
    int i = r / WW2, j = r % WW2;
    int si = i >= SHIFT ? i - SHIFT : i + (HH - SHIFT);
    int sj = j >= SHIFT ? j - SHIFT : j + (WW2 - SHIFT);
    int win = bi * NWIN + (si / WS) * 8 + (sj / WS);
    int tok = (si % WS) * WS + (sj % WS);
    const float* xp = x + (size_t)t * DIM;
    const unsigned short* ap = attn_o + ((size_t)(win * NTOK + tok)) * DIM;
    #pragma unroll
    for (int wti = 0; wti < 2; ++wti) {
      int col = (wave * 2 + wti) * 16 + g * 4;
      float4 xv = *(const float4*)(xp + col);
      ushort4 av = *(const ushort4*)(ap + col);
      float4 b4 = *(const float4*)(b2 + col);
      float4 ov;
      ov.x = xv.x + bf2f(av.x) + o[wti][nt][0] + b4.x;
      ov.y = xv.y + bf2f(av.y) + o[wti][nt][1] + b4.y;
      ov.z = xv.z + bf2f(av.z) + o[wti][nt][2] + b4.z;
      ov.w = xv.w + bf2f(av.w) + o[wti][nt][3] + b4.w;
      *(float4*)(out + (size_t)t * DIM + col) = ov;
    }
  }
}

extern "C" void kernel_launch(void* const* d_in, const int* in_sizes, int n_in,
                              void* d_out, int out_size, void* d_ws, size_t ws_size,
                              hipStream_t stream) {
  const float* x       = (const float*)d_in[0];
  const float* qkv_w   = (const float*)d_in[1];
  const float* qkv_b   = (const float*)d_in[2];
  const float* proj_w  = (const float*)d_in[3];
  const float* proj_b  = (const float*)d_in[4];
  const float* rpb     = (const float*)d_in[5];
  const float* n1w     = (const float*)d_in[6];
  const float* n1b     = (const float*)d_in[7];
  const float* n2w     = (const float*)d_in[8];
  const float* n2b     = (const float*)d_in[9];
  const float* mlp_w1  = (const float*)d_in[10];
  const float* mlp_b1  = (const float*)d_in[11];
  const float* mlp_w2  = (const float*)d_in[12];
  const float* mlp_b2  = (const float*)d_in[13];
  float* out = (float*)d_out;

  char* ws = (char*)d_ws;
  const size_t TOKB = (size_t)TOKENS * DIM * 2;     // 51,380,224 B
  unsigned short* attn_o = (unsigned short*)(ws);
  unsigned short* qkvwT  = (unsigned short*)(ws + TOKB);
  unsigned short* projwT = (unsigned short*)(ws + TOKB + 98304);
  unsigned short* w1T    = (unsigned short*)(ws + TOKB + 98304 + 32768);
  unsigned short* w2T    = (unsigned short*)(ws + TOKB + 98304 + 32768 + 131072);
  float*          tbl    = (float*)(ws + TOKB + 98304 + 32768 + 131072 + 131072);  // 262144 B

  k_prep<<<768, 256, 0, stream>>>(qkv_w, proj_w, mlp_w1, mlp_w2, qkvwT, projwT, w1T, w2T);
  k_tbl<<<256, 256, 0, stream>>>(rpb, tbl);
  k_attn<<<WINDOWS, 256, 0, stream>>>(x, n1w, n1b, qkvwT, qkv_b, projwT, proj_b, tbl, attn_o);
  k_mlp<<<TOKENS / 64, 256, 0, stream>>>(x, attn_o, n2w, n2b, w1T, mlp_b1, w2T, mlp_b2, out);
}